// Round 8
// baseline (159.325 us; speedup 1.0000x reference)
//
#include <hip/hip_runtime.h>
#include <hip/hip_bf16.h>

#define N_NODES 4096
#define IN_DIM 1024
#define OUT_DIM 512
#define NUM_HEADS 4
#define HEAD_DIM 128
#define TOP_K 16
#define NEG_SLOPE 0.2f

typedef __attribute__((ext_vector_type(8))) short bf16x8;
typedef __attribute__((ext_vector_type(4))) float f32x4;

typedef __attribute__((address_space(3))) unsigned as3_u32;
typedef const __attribute__((address_space(1))) unsigned as1_u32;

static __device__ __forceinline__ void gld16(const void* g, void* l) {
    __builtin_amdgcn_global_load_lds((as1_u32*)g, (as3_u32*)l, 16, 0, 0);
}

__device__ __forceinline__ unsigned short f2bf(float f) {
    unsigned u = __float_as_uint(f);
    unsigned r = u + 0x7FFFu + ((u >> 16) & 1u);   // round-to-nearest-even
    return (unsigned short)(r >> 16);
}
__device__ __forceinline__ float bf2f(unsigned short h) {
    return __uint_as_float(((unsigned)h) << 16);
}

// ---------------------------------------------------------------------------
// Prep (fused): f32 -> swizzled hi|lo bf16 for x and W, plus zero-init of
// s_src/s_dst.  Chunk at position c ^ (row&7), row stride 2048 ushorts.
// ---------------------------------------------------------------------------
__device__ __forceinline__ void conv_row(const float* __restrict__ src,
                                         unsigned short* __restrict__ dst, int t)
{
    int row = t >> 7, rem = t & 127, kb = rem >> 2, c = rem & 3;
    const float* s = src + (size_t)row * IN_DIM + kb * 32 + c * 8;
    float4 v0 = *(const float4*)s;
    float4 v1 = *(const float4*)(s + 4);
    float vv[8] = {v0.x, v0.y, v0.z, v0.w, v1.x, v1.y, v1.z, v1.w};
    bf16x8 H, L;
#pragma unroll
    for (int e = 0; e < 8; ++e) {
        unsigned short h = f2bf(vv[e]);
        H[e] = (short)h;
        L[e] = (short)f2bf(vv[e] - bf2f(h));
    }
    int sw = row & 7;
    unsigned short* base = dst + (size_t)row * 2048 + kb * 64;
    *(bf16x8*)(base + ((c ^ sw) << 3))       = H;
    *(bf16x8*)(base + (((c + 4) ^ sw) << 3)) = L;
}

__global__ __launch_bounds__(256) void prep_kernel(
    const float* __restrict__ x, const float* __restrict__ W,
    unsigned short* __restrict__ xc, unsigned short* __restrict__ wc,
    float* __restrict__ szero)
{
    int b = blockIdx.x, tid = threadIdx.x;
    if (b < 2048) {
        conv_row(x, xc, b * 256 + tid);
    } else if (b < 2304) {
        conv_row(W, wc, (b - 2048) * 256 + tid);
    } else {
        int t = (b - 2304) * 256 + tid;
        ((float4*)szero)[t] = (float4){0.f, 0.f, 0.f, 0.f};
    }
}

// ---------------------------------------------------------------------------
// GEMM + fused scores.  Tile 128x64, BK=32, 4 waves (2x2), wave-tile 64x32.
// Depth-2 pipeline, SIX static named LDS buffers, counted vmcnt(6).
// XCD swizzle: xcd=id&7 owns bm in [4*xcd,4*xcd+4) x all bn -> 4MB = its L2.
// Wh stored as bf16 (only the aggregate gather consumes it).
// ---------------------------------------------------------------------------
#define GBM 128
#define GBN 64

__global__ __launch_bounds__(256) void gemm_kernel(
    const unsigned short* __restrict__ xc, const unsigned short* __restrict__ wc,
    const float* __restrict__ a, unsigned short* __restrict__ Whb,
    float* __restrict__ s_src, float* __restrict__ s_dst)
{
    __shared__ __align__(16) unsigned short A0[GBM * 64];   // 16 KB each
    __shared__ __align__(16) unsigned short A1[GBM * 64];
    __shared__ __align__(16) unsigned short A2[GBM * 64];
    __shared__ __align__(16) unsigned short B0[GBN * 64];   //  8 KB each
    __shared__ __align__(16) unsigned short B1[GBN * 64];
    __shared__ __align__(16) unsigned short B2[GBN * 64];

    const int tid = threadIdx.x;
    const int id  = blockIdx.x;               // 256 blocks
    const int xcd = id & 7, seq = id >> 3;    // seq 0..31
    const int bm  = xcd * 4 + (seq >> 3), bn = seq & 7;

    const int wave = tid >> 6, lane = tid & 63;
    const int wm = wave >> 1, wn = wave & 1;  // 2x2 wave grid
    const int lr = lane & 15, lk = lane >> 4;

    f32x4 acc[4][2];
#pragma unroll
    for (int i = 0; i < 4; ++i)
#pragma unroll
        for (int j = 0; j < 2; ++j) acc[i][j] = (f32x4){0.f, 0.f, 0.f, 0.f};

#define STAGE(Abuf, Bbuf, kt) do {                                            \
        size_t koff = (size_t)(kt) * 128;                                     \
        _Pragma("unroll")                                                     \
        for (int q = 0; q < 4; ++q) {          /* A: 16 KB = 1024 chunks */   \
            int ci = q * 256 + tid;                                           \
            int row = ci >> 3, p = ci & 7;                                    \
            gld16((const char*)xc + ((size_t)(bm * GBM + row) * 4096 + koff + p * 16), \
                  (char*)(Abuf) + (size_t)ci * 16);                           \
        }                                                                     \
        _Pragma("unroll")                                                     \
        for (int q = 0; q < 2; ++q) {          /* B: 8 KB = 512 chunks */     \
            int ci = q * 256 + tid;                                           \
            int row = ci >> 3, p = ci & 7;                                    \
            gld16((const char*)wc + ((size_t)(bn * GBN + row) * 4096 + koff + p * 16), \
                  (char*)(Bbuf) + (size_t)ci * 16);                           \
        }                                                                     \
    } while (0)

#define COMPUTE(Abuf, Bbuf) do {                                              \
        bf16x8 bh[2], bl[2];                                                  \
        _Pragma("unroll")                                                     \
        for (int ni = 0; ni < 2; ++ni) {                                      \
            int rb = wn * 32 + ni * 16 + lr; int swb = rb & 7;                \
            bh[ni] = *(const bf16x8*)&(Bbuf)[rb * 64 + ((lk ^ swb) << 3)];    \
            bl[ni] = *(const bf16x8*)&(Bbuf)[rb * 64 + (((4 + lk) ^ swb) << 3)]; \
        }                                                                     \
        __builtin_amdgcn_s_setprio(1);                                        \
        _Pragma("unroll")                                                     \
        for (int mi = 0; mi < 4; ++mi) {                                      \
            int r = wm * 64 + mi * 16 + lr; int sw = r & 7;                   \
            bf16x8 ah = *(const bf16x8*)&(Abuf)[r * 64 + ((lk ^ sw) << 3)];   \
            bf16x8 al = *(const bf16x8*)&(Abuf)[r * 64 + (((4 + lk) ^ sw) << 3)]; \
            _Pragma("unroll")                                                 \
            for (int ni = 0; ni < 2; ++ni) {                                  \
                acc[mi][ni] = __builtin_amdgcn_mfma_f32_16x16x32_bf16(ah, bh[ni], acc[mi][ni], 0, 0, 0); \
                acc[mi][ni] = __builtin_amdgcn_mfma_f32_16x16x32_bf16(ah, bl[ni], acc[mi][ni], 0, 0, 0); \
                acc[mi][ni] = __builtin_amdgcn_mfma_f32_16x16x32_bf16(al, bh[ni], acc[mi][ni], 0, 0, 0); \
            }                                                                 \
        }                                                                     \
        __builtin_amdgcn_s_setprio(0);                                        \
    } while (0)

#define BODY(Ac, Bc, An, Bn, ktn, W) do {                                     \
        asm volatile("s_waitcnt vmcnt(" #W ")" ::: "memory");                 \
        __builtin_amdgcn_s_barrier();                                         \
        asm volatile("" ::: "memory");                                        \
        if ((ktn) < 32) STAGE(An, Bn, ktn);                                   \
        COMPUTE(Ac, Bc);                                                      \
    } while (0)

    STAGE(A0, B0, 0);
    STAGE(A1, B1, 1);

    for (int i = 0; i < 10; ++i) {
        int t = i * 3;
        BODY(A0, B0, A2, B2, t + 2, 6);
        BODY(A1, B1, A0, B0, t + 3, 6);
        BODY(A2, B2, A1, B1, t + 4, 6);
    }
    BODY(A0, B0, A2, B2, 32, 6);
    asm volatile("s_waitcnt vmcnt(0)" ::: "memory");
    __builtin_amdgcn_s_barrier();
    asm volatile("" ::: "memory");
    COMPUTE(A1, B1);

#undef BODY
#undef COMPUTE
#undef STAGE

    // ---- epilogue: bf16 Wh store + fused score partials (f32 precision) ----
    const int h = bn >> 1;                     // head uniform per block
    float ca[2], cb[2];
#pragma unroll
    for (int ni = 0; ni < 2; ++ni) {
        int dcol = (bn & 1) * 64 + wn * 32 + ni * 16 + lr;
        ca[ni] = a[dcol];
        cb[ni] = a[HEAD_DIM + dcol];
    }
#pragma unroll
    for (int mi = 0; mi < 4; ++mi) {
        float ss[4] = {0.f, 0.f, 0.f, 0.f}, sd[4] = {0.f, 0.f, 0.f, 0.f};
#pragma unroll
        for (int ni = 0; ni < 2; ++ni) {
            int col_g = bn * GBN + wn * 32 + ni * 16 + lr;
#pragma unroll
            for (int r = 0; r < 4; ++r) {
                int row_g = bm * GBM + wm * 64 + mi * 16 + lk * 4 + r;
                float v = acc[mi][ni][r];
                Whb[(size_t)row_g * OUT_DIM + col_g] = f2bf(v);
                ss[r] += v * ca[ni];
                sd[r] += v * cb[ni];
            }
        }
#pragma unroll
        for (int s = 1; s < 16; s <<= 1)
#pragma unroll
            for (int r = 0; r < 4; ++r) {
                ss[r] += __shfl_xor(ss[r], s);
                sd[r] += __shfl_xor(sd[r], s);
            }
        if (lr == 0) {
#pragma unroll
            for (int r = 0; r < 4; ++r) {
                int row_g = bm * GBM + wm * 64 + mi * 16 + lk * 4 + r;
                atomicAdd(&s_src[row_g * NUM_HEADS + h], ss[r]);
                atomicAdd(&s_dst[row_g * NUM_HEADS + h], sd[r]);
            }
        }
    }
}

// ---------------------------------------------------------------------------
// Top-16, v3: one row per block, 4 waves.  Filter on the fly (no register
// row-hold): each lane tests its 16 values as they arrive, ballot-compacts
// candidates (key = orderable-value | inverted-index) into per-wave LDS
// segments.  Wave 0 merges <=256 candidates via 16 argmax rounds over 4
// regs + butterfly.  Exact LDS-staged fallback if filter under/overflows.
// ---------------------------------------------------------------------------
#define TK_THRESH 0.988f

__global__ __launch_bounds__(256) void topk_kernel(
    const float* __restrict__ adj, int* __restrict__ topk)
{
    const int row  = blockIdx.x;
    const int tid  = threadIdx.x;
    const int wave = tid >> 6, lane = tid & 63;
    const float* rp = adj + (size_t)row * N_NODES;

    __shared__ unsigned long long cand[4][64];
    __shared__ int wcnt[4];
    __shared__ float srow[N_NODES];   // fallback stage (16 KB)

    // issue all 4 loads up front; lane covers wave*1024 + i*256 + lane*4
    float4 q0 = *(const float4*)(rp + wave * 1024 + 0 * 256 + lane * 4);
    float4 q1 = *(const float4*)(rp + wave * 1024 + 1 * 256 + lane * 4);
    float4 q2 = *(const float4*)(rp + wave * 1024 + 2 * 256 + lane * 4);
    float4 q3 = *(const float4*)(rp + wave * 1024 + 3 * 256 + lane * 4);

    const unsigned long long lmask = (1ull << lane) - 1ull;
    int cnt = 0;

#define FILT(qv, i, e, comp) do {                                             \
        float val = (qv).comp;                                                \
        int g = wave * 1024 + (i) * 256 + lane * 4 + (e);                     \
        bool p = val >= TK_THRESH;                                            \
        unsigned long long m = __ballot(p);                                   \
        if (p) {                                                              \
            int pos = cnt + __popcll(m & lmask);                              \
            if (pos < 64) {                                                   \
                unsigned b  = __float_as_uint(val);                           \
                unsigned mo = b ^ (unsigned)(((int)b >> 31) | 0x80000000);    \
                cand[wave][pos] =                                             \
                    ((unsigned long long)mo << 32) | (unsigned)(N_NODES - 1 - g); \
            }                                                                 \
        }                                                                     \
        cnt += __popcll(m);                                                   \
    } while (0)

    FILT(q0, 0, 0, x); FILT(q0, 0, 1, y); FILT(q0, 0, 2, z); FILT(q0, 0, 3, w);
    FILT(q1, 1, 0, x); FILT(q1, 1, 1, y); FILT(q1, 1, 2, z); FILT(q1, 1, 3, w);
    FILT(q2, 2, 0, x); FILT(q2, 2, 1, y); FILT(q2, 2, 2, z); FILT(q2, 2, 3, w);
    FILT(q3, 3, 0, x); FILT(q3, 3, 1, y); FILT(q3, 3, 2, z); FILT(q3, 3, 3, w);
#undef FILT

    if (lane == 0) wcnt[wave] = cnt;
    __syncthreads();

    const int c0n = wcnt[0], c1n = wcnt[1], c2n = wcnt[2], c3n = wcnt[3];
    const int total = c0n + c1n + c2n + c3n;
    const bool ok = (total >= TOP_K) &&
                    (c0n <= 64) && (c1n <= 64) && (c2n <= 64) && (c3n <= 64);
    int* op = topk + (size_t)row * TOP_K;

    if (ok) {
        if (wave == 0) {
            unsigned long long k0 = lane < c0n ? cand[0][lane] : 0ull;
            unsigned long long k1 = lane < c1n ? cand[1][lane] : 0ull;
            unsigned long long k2 = lane < c2n ? cand[2][lane] : 0ull;
            unsigned long long k3 = lane < c3n ? cand[3][lane] : 0ull;
            for (int r = 0; r < TOP_K; ++r) {
                unsigned long long a01 = k0 > k1 ? k0 : k1;
                unsigned long long a23 = k2 > k3 ? k2 : k3;
                unsigned long long b = a01 > a23 ? a01 : a23;
#pragma unroll
                for (int m = 1; m < 64; m <<= 1) {
                    unsigned long long o = __shfl_xor(b, m);
                    b = o > b ? o : b;
                }
                if (lane == 0) op[r] = N_NODES - 1 - (int)(unsigned)(b & 0xFFFFFFFFu);
                if (k0 == b) k0 = 0ull;
                if (k1 == b) k1 = 0ull;
                if (k2 == b) k2 = 0ull;
                if (k3 == b) k3 = 0ull;
            }
        }
    } else {
        // exact fallback: stage full row to LDS, wave 0 does 16 argmax rounds
        int base = wave * 1024 + lane * 4;
        *(float4*)&srow[base + 0 * 256] = q0;
        *(float4*)&srow[base + 1 * 256] = q1;
        *(float4*)&srow[base + 2 * 256] = q2;
        *(float4*)&srow[base + 3 * 256] = q3;
        __syncthreads();
        if (wave == 0) {
            for (int r = 0; r < TOP_K; ++r) {
                float bv = -INFINITY; int bg = 0x7fffffff;
                for (int j = 0; j < 64; ++j) {
                    int g = j * 64 + lane;
                    float val = srow[g];
                    bool better = (val > bv) || (val == bv && g < bg);
                    bv = better ? val : bv;
                    bg = better ? g : bg;
                }
#pragma unroll
                for (int m = 1; m < 64; m <<= 1) {
                    float ov = __shfl_xor(bv, m);
                    int   og = __shfl_xor(bg, m);
                    bool better = (ov > bv) || (ov == bv && og < bg);
                    bv = better ? ov : bv;
                    bg = better ? og : bg;
                }
                if (lane == 0) { op[r] = bg; srow[bg] = -INFINITY; }
            }
        }
    }
}

// ---------------------------------------------------------------------------
// Aggregate (bf16 Wh): wave-parallel softmax, then gather with 4 neighbor-
// groups x 64 col-octets (16B bf16x8 loads), conflict-free part[3][8][64]
// combine, ELU, f32 store.
// ---------------------------------------------------------------------------
__global__ __launch_bounds__(256) void aggregate_kernel(
    const unsigned short* __restrict__ Whb, const int* __restrict__ topk,
    const float* __restrict__ s_src, const float* __restrict__ s_dst,
    float* __restrict__ out)
{
    const int i = blockIdx.x, t = threadIdx.x;
    __shared__ int   sidx[TOP_K];
    __shared__ float salpha[TOP_K][NUM_HEADS];
    __shared__ float part[3][8][64];

    if (t < 64) {
        int idxv = 0;
        if (t < TOP_K) { idxv = topk[(size_t)i * TOP_K + t]; sidx[t] = idxv; }
        int m = t >> 2, h = t & 3;
        int im = __shfl(idxv, m);
        float e = s_src[i * NUM_HEADS + h] + s_dst[im * NUM_HEADS + h];
        e = (e >= 0.f) ? e : NEG_SLOPE * e;
        float mx = e;
#pragma unroll
        for (int s = 4; s < 64; s <<= 1) mx = fmaxf(mx, __shfl_xor(mx, s));
        float ex = expf(e - mx);
        float sum = ex;
#pragma unroll
        for (int s = 4; s < 64; s <<= 1) sum += __shfl_xor(sum, s);
        salpha[m][h] = ex / sum;
    }
    __syncthreads();

    const int g = t >> 6, o = t & 63;       // group g: neighbors 4g..4g+3
    const int h = o >> 4;                   // cols 8o..8o+7 all in head h
    float acc8[8] = {0.f, 0.f, 0.f, 0.f, 0.f, 0.f, 0.f, 0.f};
#pragma unroll
    for (int q = 0; q < 4; ++q) {
        int m = g * 4 + q;
        float al = salpha[m][h];
        bf16x8 v = *(const bf16x8*)&Whb[(size_t)sidx[m] * OUT_DIM + o * 8];
#pragma unroll
        for (int e = 0; e < 8; ++e)
            acc8[e] += al * bf2f((unsigned short)v[e]);
    }
    if (g) {
#pragma unroll
        for (int e = 0; e < 8; ++e) part[g - 1][e][o] = acc8[e];
    }
    __syncthreads();
    if (!g) {
        float r8[8];
#pragma unroll
        for (int e = 0; e < 8; ++e) {
            float s = acc8[e] + part[0][e][o] + part[1][e][o] + part[2][e][o];
            r8[e] = s > 0.f ? s : expf(s) - 1.f;
        }
        float4 lo = (float4){r8[0], r8[1], r8[2], r8[3]};
        float4 hi = (float4){r8[4], r8[5], r8[6], r8[7]};
        *(float4*)(out + (size_t)i * OUT_DIM + o * 8)     = lo;
        *(float4*)(out + (size_t)i * OUT_DIM + o * 8 + 4) = hi;
    }
}

// ---------------------------------------------------------------------------
extern "C" void kernel_launch(void* const* d_in, const int* in_sizes, int n_in,
                              void* d_out, int out_size, void* d_ws, size_t ws_size,
                              hipStream_t stream) {
    const float* x   = (const float*)d_in[0];
    const float* adj = (const float*)d_in[1];
    const float* W   = (const float*)d_in[2];
    const float* a   = (const float*)d_in[3];
    float* out = (float*)d_out;

    char* ws = (char*)d_ws;
    unsigned short* Whb   = (unsigned short*)ws;                         //  4 MB
    unsigned short* xc    = (unsigned short*)(ws + (8u << 20));          // 16 MB
    unsigned short* wc    = (unsigned short*)(ws + (24u << 20));         //  2 MB
    float*          s_src = (float*)(ws + (26u << 20));                  // 64 KB
    float*          s_dst = s_src + N_NODES * NUM_HEADS;                 // 64 KB
    int*            topkb = (int*)(s_dst + N_NODES * NUM_HEADS);         // 256 KB

    prep_kernel<<<2336, 256, 0, stream>>>(x, W, xc, wc, s_src);
    gemm_kernel<<<256, 256, 0, stream>>>(xc, wc, a, Whb, s_src, s_dst);
    topk_kernel<<<N_NODES, 256, 0, stream>>>(adj, topkb);
    aggregate_kernel<<<N_NODES, 256, 0, stream>>>(Whb, topkb, s_src, s_dst, out);
}

// Round 9
// 147.320 us; speedup vs baseline: 1.0815x; 1.0815x over previous
//
#include <hip/hip_runtime.h>
#include <hip/hip_bf16.h>

#define N_NODES 4096
#define IN_DIM 1024
#define OUT_DIM 512
#define NUM_HEADS 4
#define HEAD_DIM 128
#define TOP_K 16
#define NEG_SLOPE 0.2f

typedef __attribute__((ext_vector_type(8))) short bf16x8;
typedef __attribute__((ext_vector_type(4))) float f32x4;

typedef __attribute__((address_space(3))) unsigned as3_u32;
typedef const __attribute__((address_space(1))) unsigned as1_u32;

static __device__ __forceinline__ void gld16(const void* g, void* l) {
    __builtin_amdgcn_global_load_lds((as1_u32*)g, (as3_u32*)l, 16, 0, 0);
}

__device__ __forceinline__ unsigned short f2bf(float f) {
    unsigned u = __float_as_uint(f);
    unsigned r = u + 0x7FFFu + ((u >> 16) & 1u);   // round-to-nearest-even
    return (unsigned short)(r >> 16);
}
__device__ __forceinline__ float bf2f(unsigned short h) {
    return __uint_as_float(((unsigned)h) << 16);
}

// ---------------------------------------------------------------------------
// conv_row: f32 row-block -> swizzled hi|lo bf16 (chunk c ^ (row&7)).
// ---------------------------------------------------------------------------
__device__ __forceinline__ void conv_row(const float* __restrict__ src,
                                         unsigned short* __restrict__ dst, int t)
{
    int row = t >> 7, rem = t & 127, kb = rem >> 2, c = rem & 3;
    const float* s = src + (size_t)row * IN_DIM + kb * 32 + c * 8;
    float4 v0 = *(const float4*)s;
    float4 v1 = *(const float4*)(s + 4);
    float vv[8] = {v0.x, v0.y, v0.z, v0.w, v1.x, v1.y, v1.z, v1.w};
    bf16x8 H, L;
#pragma unroll
    for (int e = 0; e < 8; ++e) {
        unsigned short h = f2bf(vv[e]);
        H[e] = (short)h;
        L[e] = (short)f2bf(vv[e] - bf2f(h));
    }
    int sw = row & 7;
    unsigned short* base = dst + (size_t)row * 2048 + kb * 64;
    *(bf16x8*)(base + ((c ^ sw) << 3))       = H;
    *(bf16x8*)(base + (((c + 4) ^ sw) << 3)) = L;
}

// ---------------------------------------------------------------------------
// topk body (R8 v3, unchanged): filter-on-the-fly + wave-0 merge; exact
// LDS-staged fallback.
// ---------------------------------------------------------------------------
#define TK_THRESH 0.988f

__device__ __forceinline__ void topk_body(int row, const float* __restrict__ adj,
                                          int* __restrict__ topkb)
{
    const int tid  = threadIdx.x;
    const int wave = tid >> 6, lane = tid & 63;
    const float* rp = adj + (size_t)row * N_NODES;

    __shared__ unsigned long long cand[4][64];
    __shared__ int wcnt[4];
    __shared__ float srow[N_NODES];   // fallback stage (16 KB)

    float4 q0 = *(const float4*)(rp + wave * 1024 + 0 * 256 + lane * 4);
    float4 q1 = *(const float4*)(rp + wave * 1024 + 1 * 256 + lane * 4);
    float4 q2 = *(const float4*)(rp + wave * 1024 + 2 * 256 + lane * 4);
    float4 q3 = *(const float4*)(rp + wave * 1024 + 3 * 256 + lane * 4);

    const unsigned long long lmask = (1ull << lane) - 1ull;
    int cnt = 0;

#define FILT(qv, i, e, comp) do {                                             \
        float val = (qv).comp;                                                \
        int g = wave * 1024 + (i) * 256 + lane * 4 + (e);                     \
        bool p = val >= TK_THRESH;                                            \
        unsigned long long m = __ballot(p);                                   \
        if (p) {                                                              \
            int pos = cnt + __popcll(m & lmask);                              \
            if (pos < 64) {                                                   \
                unsigned b  = __float_as_uint(val);                           \
                unsigned mo = b ^ (unsigned)(((int)b >> 31) | 0x80000000);    \
                cand[wave][pos] =                                             \
                    ((unsigned long long)mo << 32) | (unsigned)(N_NODES - 1 - g); \
            }                                                                 \
        }                                                                     \
        cnt += __popcll(m);                                                   \
    } while (0)

    FILT(q0, 0, 0, x); FILT(q0, 0, 1, y); FILT(q0, 0, 2, z); FILT(q0, 0, 3, w);
    FILT(q1, 1, 0, x); FILT(q1, 1, 1, y); FILT(q1, 1, 2, z); FILT(q1, 1, 3, w);
    FILT(q2, 2, 0, x); FILT(q2, 2, 1, y); FILT(q2, 2, 2, z); FILT(q2, 2, 3, w);
    FILT(q3, 3, 0, x); FILT(q3, 3, 1, y); FILT(q3, 3, 2, z); FILT(q3, 3, 3, w);
#undef FILT

    if (lane == 0) wcnt[wave] = cnt;
    __syncthreads();

    const int c0n = wcnt[0], c1n = wcnt[1], c2n = wcnt[2], c3n = wcnt[3];
    const int total = c0n + c1n + c2n + c3n;
    const bool ok = (total >= TOP_K) &&
                    (c0n <= 64) && (c1n <= 64) && (c2n <= 64) && (c3n <= 64);
    int* op = topkb + (size_t)row * TOP_K;

    if (ok) {
        if (wave == 0) {
            unsigned long long k0 = lane < c0n ? cand[0][lane] : 0ull;
            unsigned long long k1 = lane < c1n ? cand[1][lane] : 0ull;
            unsigned long long k2 = lane < c2n ? cand[2][lane] : 0ull;
            unsigned long long k3 = lane < c3n ? cand[3][lane] : 0ull;
            for (int r = 0; r < TOP_K; ++r) {
                unsigned long long a01 = k0 > k1 ? k0 : k1;
                unsigned long long a23 = k2 > k3 ? k2 : k3;
                unsigned long long b = a01 > a23 ? a01 : a23;
#pragma unroll
                for (int m = 1; m < 64; m <<= 1) {
                    unsigned long long o = __shfl_xor(b, m);
                    b = o > b ? o : b;
                }
                if (lane == 0) op[r] = N_NODES - 1 - (int)(unsigned)(b & 0xFFFFFFFFu);
                if (k0 == b) k0 = 0ull;
                if (k1 == b) k1 = 0ull;
                if (k2 == b) k2 = 0ull;
                if (k3 == b) k3 = 0ull;
            }
        }
    } else {
        int base = wave * 1024 + lane * 4;
        *(float4*)&srow[base + 0 * 256] = q0;
        *(float4*)&srow[base + 1 * 256] = q1;
        *(float4*)&srow[base + 2 * 256] = q2;
        *(float4*)&srow[base + 3 * 256] = q3;
        __syncthreads();
        if (wave == 0) {
            for (int r = 0; r < TOP_K; ++r) {
                float bv = -INFINITY; int bg = 0x7fffffff;
                for (int j = 0; j < 64; ++j) {
                    int g = j * 64 + lane;
                    float val = srow[g];
                    bool better = (val > bv) || (val == bv && g < bg);
                    bv = better ? val : bv;
                    bg = better ? g : bg;
                }
#pragma unroll
                for (int m = 1; m < 64; m <<= 1) {
                    float ov = __shfl_xor(bv, m);
                    int   og = __shfl_xor(bg, m);
                    bool better = (ov > bv) || (ov == bv && og < bg);
                    bv = better ? ov : bv;
                    bg = better ? og : bg;
                }
                if (lane == 0) { op[r] = bg; srow[bg] = -INFINITY; }
            }
        }
    }
}

// ---------------------------------------------------------------------------
// Fused launch 1: topk (blocks 0..4095, dispatched first) + prep conversion
// (blocks 4096..6399).  Independent work; prep backfills behind topk's
// memory stream.
// ---------------------------------------------------------------------------
__global__ __launch_bounds__(256) void prep_topk_kernel(
    const float* __restrict__ x, const float* __restrict__ W,
    unsigned short* __restrict__ xc, unsigned short* __restrict__ wc,
    const float* __restrict__ adj, int* __restrict__ topkb)
{
    int b = blockIdx.x, tid = threadIdx.x;
    if (b < 4096) {
        topk_body(b, adj, topkb);
    } else if (b < 6144) {
        conv_row(x, xc, (b - 4096) * 256 + tid);
    } else {
        conv_row(W, wc, (b - 6144) * 256 + tid);
    }
}

// ---------------------------------------------------------------------------
// GEMM + fused scores.  Tile 128x64, BK=32, 4 waves (2x2), wave-tile 64x32.
// Depth-3 pipeline: FOUR static named LDS buffers (96 KB), steady-state
// s_waitcnt vmcnt(12) -> 2 staged tiles always in flight across barriers.
// Score partials: each (parity, wn) writes a private slot (no atomics).
// ---------------------------------------------------------------------------
#define GBM 128
#define GBN 64

__global__ __launch_bounds__(256) void gemm_kernel(
    const unsigned short* __restrict__ xc, const unsigned short* __restrict__ wc,
    const float* __restrict__ a, unsigned short* __restrict__ Whb,
    float* __restrict__ spart)
{
    __shared__ __align__(16) unsigned short A0[GBM * 64];   // 16 KB each
    __shared__ __align__(16) unsigned short A1[GBM * 64];
    __shared__ __align__(16) unsigned short A2[GBM * 64];
    __shared__ __align__(16) unsigned short A3[GBM * 64];
    __shared__ __align__(16) unsigned short B0[GBN * 64];   //  8 KB each
    __shared__ __align__(16) unsigned short B1[GBN * 64];
    __shared__ __align__(16) unsigned short B2[GBN * 64];
    __shared__ __align__(16) unsigned short B3[GBN * 64];

    const int tid = threadIdx.x;
    const int id  = blockIdx.x;               // 256 blocks
    const int xcd = id & 7, seq = id >> 3;    // seq 0..31
    const int bm  = xcd * 4 + (seq >> 3), bn = seq & 7;

    const int wave = tid >> 6, lane = tid & 63;
    const int wm = wave >> 1, wn = wave & 1;  // 2x2 wave grid
    const int lr = lane & 15, lk = lane >> 4;

    f32x4 acc[4][2];
#pragma unroll
    for (int i = 0; i < 4; ++i)
#pragma unroll
        for (int j = 0; j < 2; ++j) acc[i][j] = (f32x4){0.f, 0.f, 0.f, 0.f};

#define STAGE(Abuf, Bbuf, kt) do {                                            \
        size_t koff = (size_t)(kt) * 128;                                     \
        _Pragma("unroll")                                                     \
        for (int q = 0; q < 4; ++q) {          /* A: 16 KB = 1024 chunks */   \
            int ci = q * 256 + tid;                                           \
            int row = ci >> 3, p = ci & 7;                                    \
            gld16((const char*)xc + ((size_t)(bm * GBM + row) * 4096 + koff + p * 16), \
                  (char*)(Abuf) + (size_t)ci * 16);                           \
        }                                                                     \
        _Pragma("unroll")                                                     \
        for (int q = 0; q < 2; ++q) {          /* B: 8 KB = 512 chunks */     \
            int ci = q * 256 + tid;                                           \
            int row = ci >> 3, p = ci & 7;                                    \
            gld16((const char*)wc + ((size_t)(bn * GBN + row) * 4096 + koff + p * 16), \
                  (char*)(Bbuf) + (size_t)ci * 16);                           \
        }                                                                     \
    } while (0)

#define COMPUTE(Abuf, Bbuf) do {                                              \
        bf16x8 bh[2], bl[2];                                                  \
        _Pragma("unroll")                                                     \
        for (int ni = 0; ni < 2; ++ni) {                                      \
            int rb = wn * 32 + ni * 16 + lr; int swb = rb & 7;                \
            bh[ni] = *(const bf16x8*)&(Bbuf)[rb * 64 + ((lk ^ swb) << 3)];    \
            bl[ni] = *(const bf16x8*)&(Bbuf)[rb * 64 + (((4 + lk) ^ swb) << 3)]; \
        }                                                                     \
        __builtin_amdgcn_s_setprio(1);                                        \
        _Pragma("unroll")                                                     \
        for (int mi = 0; mi < 4; ++mi) {                                      \
            int r = wm * 64 + mi * 16 + lr; int sw = r & 7;                   \
            bf16x8 ah = *(const bf16x8*)&(Abuf)[r * 64 + ((lk ^ sw) << 3)];   \
            bf16x8 al = *(const bf16x8*)&(Abuf)[r * 64 + (((4 + lk) ^ sw) << 3)]; \
            _Pragma("unroll")                                                 \
            for (int ni = 0; ni < 2; ++ni) {                                  \
                acc[mi][ni] = __builtin_amdgcn_mfma_f32_16x16x32_bf16(ah, bh[ni], acc[mi][ni], 0, 0, 0); \
                acc[mi][ni] = __builtin_amdgcn_mfma_f32_16x16x32_bf16(ah, bl[ni], acc[mi][ni], 0, 0, 0); \
                acc[mi][ni] = __builtin_amdgcn_mfma_f32_16x16x32_bf16(al, bh[ni], acc[mi][ni], 0, 0, 0); \
            }                                                                 \
        }                                                                     \
        __builtin_amdgcn_s_setprio(0);                                        \
    } while (0)

#define BODY(Ac, Bc, An, Bn, ktn, W) do {                                     \
        asm volatile("s_waitcnt vmcnt(" #W ")" ::: "memory");                 \
        __builtin_amdgcn_s_barrier();                                         \
        asm volatile("" ::: "memory");                                        \
        if ((ktn) < 32) STAGE(An, Bn, ktn);                                   \
        COMPUTE(Ac, Bc);                                                      \
    } while (0)

    STAGE(A0, B0, 0);
    STAGE(A1, B1, 1);
    STAGE(A2, B2, 2);

    for (int i = 0; i < 7; ++i) {             // t = 0..27
        BODY(A0, B0, A3, B3, i * 4 + 3, 12);
        BODY(A1, B1, A0, B0, i * 4 + 4, 12);
        BODY(A2, B2, A1, B1, i * 4 + 5, 12);
        BODY(A3, B3, A2, B2, i * 4 + 6, 12);
    }
    BODY(A0, B0, A3, B3, 31, 12);             // t=28, stage 31
    BODY(A1, B1, A0, B0, 33, 12);             // t=29, no stage
    asm volatile("s_waitcnt vmcnt(6)" ::: "memory");
    __builtin_amdgcn_s_barrier();
    asm volatile("" ::: "memory");
    COMPUTE(A2, B2);                          // t=30
    asm volatile("s_waitcnt vmcnt(0)" ::: "memory");
    __builtin_amdgcn_s_barrier();
    asm volatile("" ::: "memory");
    COMPUTE(A3, B3);                          // t=31

#undef BODY
#undef COMPUTE
#undef STAGE

    // ---- epilogue: bf16 Wh store + score partials to private slot ----
    const int h = bn >> 1;                     // head uniform per block
    float* sps = spart + ((size_t)((bn & 1) * 2 + wn)) * 16384;
    float* spd = spart + 65536 + ((size_t)((bn & 1) * 2 + wn)) * 16384;
    float ca[2], cb[2];
#pragma unroll
    for (int ni = 0; ni < 2; ++ni) {
        int dcol = (bn & 1) * 64 + wn * 32 + ni * 16 + lr;
        ca[ni] = a[dcol];
        cb[ni] = a[HEAD_DIM + dcol];
    }
#pragma unroll
    for (int mi = 0; mi < 4; ++mi) {
        float ss[4] = {0.f, 0.f, 0.f, 0.f}, sd[4] = {0.f, 0.f, 0.f, 0.f};
#pragma unroll
        for (int ni = 0; ni < 2; ++ni) {
            int col_g = bn * GBN + wn * 32 + ni * 16 + lr;
#pragma unroll
            for (int r = 0; r < 4; ++r) {
                int row_g = bm * GBM + wm * 64 + mi * 16 + lk * 4 + r;
                float v = acc[mi][ni][r];
                Whb[(size_t)row_g * OUT_DIM + col_g] = f2bf(v);
                ss[r] += v * ca[ni];
                sd[r] += v * cb[ni];
            }
        }
#pragma unroll
        for (int s = 1; s < 16; s <<= 1)
#pragma unroll
            for (int r = 0; r < 4; ++r) {
                ss[r] += __shfl_xor(ss[r], s);
                sd[r] += __shfl_xor(sd[r], s);
            }
        if (lr == 0) {
#pragma unroll
            for (int r = 0; r < 4; ++r) {
                int row_g = bm * GBM + wm * 64 + mi * 16 + lk * 4 + r;
                sps[row_g * NUM_HEADS + h] = ss[r];
                spd[row_g * NUM_HEADS + h] = sd[r];
            }
        }
    }
}

// ---------------------------------------------------------------------------
// Aggregate (bf16 Wh): wave-parallel softmax (scores = sum of 4 partial
// slots), gather 4 neighbor-groups x 64 col-octets, LDS combine, ELU.
// ---------------------------------------------------------------------------
__global__ __launch_bounds__(256) void aggregate_kernel(
    const unsigned short* __restrict__ Whb, const int* __restrict__ topk,
    const float* __restrict__ spart, float* __restrict__ out)
{
    const int i = blockIdx.x, t = threadIdx.x;
    __shared__ int   sidx[TOP_K];
    __shared__ float salpha[TOP_K][NUM_HEADS];
    __shared__ float part[3][8][64];

    if (t < 64) {
        int idxv = 0;
        if (t < TOP_K) { idxv = topk[(size_t)i * TOP_K + t]; sidx[t] = idxv; }
        int m = t >> 2, h = t & 3;
        int im = __shfl(idxv, m);
        int si = (i << 2) + h, di = (im << 2) + h;
        float e = spart[si] + spart[16384 + si] + spart[32768 + si] + spart[49152 + si]
                + spart[65536 + di] + spart[81920 + di] + spart[98304 + di] + spart[114688 + di];
        e = (e >= 0.f) ? e : NEG_SLOPE * e;
        float mx = e;
#pragma unroll
        for (int s = 4; s < 64; s <<= 1) mx = fmaxf(mx, __shfl_xor(mx, s));
        float ex = expf(e - mx);
        float sum = ex;
#pragma unroll
        for (int s = 4; s < 64; s <<= 1) sum += __shfl_xor(sum, s);
        salpha[m][h] = ex / sum;
    }
    __syncthreads();

    const int g = t >> 6, o = t & 63;       // group g: neighbors 4g..4g+3
    const int h = o >> 4;                   // cols 8o..8o+7 all in head h
    float acc8[8] = {0.f, 0.f, 0.f, 0.f, 0.f, 0.f, 0.f, 0.f};
#pragma unroll
    for (int q = 0; q < 4; ++q) {
        int m = g * 4 + q;
        float al = salpha[m][h];
        bf16x8 v = *(const bf16x8*)&Whb[(size_t)sidx[m] * OUT_DIM + o * 8];
#pragma unroll
        for (int e = 0; e < 8; ++e)
            acc8[e] += al * bf2f((unsigned short)v[e]);
    }
    if (g) {
#pragma unroll
        for (int e = 0; e < 8; ++e) part[g - 1][e][o] = acc8[e];
    }
    __syncthreads();
    if (!g) {
        float r8[8];
#pragma unroll
        for (int e = 0; e < 8; ++e) {
            float s = acc8[e] + part[0][e][o] + part[1][e][o] + part[2][e][o];
            r8[e] = s > 0.f ? s : expf(s) - 1.f;
        }
        float4 lo = (float4){r8[0], r8[1], r8[2], r8[3]};
        float4 hi = (float4){r8[4], r8[5], r8[6], r8[7]};
        *(float4*)(out + (size_t)i * OUT_DIM + o * 8)     = lo;
        *(float4*)(out + (size_t)i * OUT_DIM + o * 8 + 4) = hi;
    }
}

// ---------------------------------------------------------------------------
extern "C" void kernel_launch(void* const* d_in, const int* in_sizes, int n_in,
                              void* d_out, int out_size, void* d_ws, size_t ws_size,
                              hipStream_t stream) {
    const float* x   = (const float*)d_in[0];
    const float* adj = (const float*)d_in[1];
    const float* W   = (const float*)d_in[2];
    const float* a   = (const float*)d_in[3];
    float* out = (float*)d_out;

    char* ws = (char*)d_ws;
    unsigned short* Whb   = (unsigned short*)ws;                         //  4 MB
    unsigned short* xc    = (unsigned short*)(ws + (8u << 20));          // 16 MB
    unsigned short* wc    = (unsigned short*)(ws + (24u << 20));         //  2 MB
    float*          spart = (float*)(ws + (26u << 20));                  // 512 KB
    int*            topkb = (int*)(ws + (26u << 20) + (512u << 10));     // 256 KB

    prep_topk_kernel<<<6400, 256, 0, stream>>>(x, W, xc, wc, adj, topkb);
    gemm_kernel<<<256, 256, 0, stream>>>(xc, wc, a, Whb, spart);
    aggregate_kernel<<<N_NODES, 256, 0, stream>>>(Whb, topkb, spart, out);
}

// Round 10
// 142.155 us; speedup vs baseline: 1.1208x; 1.0363x over previous
//
#include <hip/hip_runtime.h>
#include <hip/hip_bf16.h>

#define N_NODES 4096
#define IN_DIM 1024
#define OUT_DIM 512
#define NUM_HEADS 4
#define HEAD_DIM 128
#define TOP_K 16
#define NEG_SLOPE 0.2f

typedef __attribute__((ext_vector_type(8))) short bf16x8;
typedef __attribute__((ext_vector_type(4))) float f32x4;

typedef __attribute__((address_space(3))) unsigned as3_u32;
typedef const __attribute__((address_space(1))) unsigned as1_u32;

static __device__ __forceinline__ void gld16(const void* g, void* l) {
    __builtin_amdgcn_global_load_lds((as1_u32*)g, (as3_u32*)l, 16, 0, 0);
}

__device__ __forceinline__ unsigned short f2bf(float f) {
    unsigned u = __float_as_uint(f);
    unsigned r = u + 0x7FFFu + ((u >> 16) & 1u);   // round-to-nearest-even
    return (unsigned short)(r >> 16);
}
__device__ __forceinline__ float bf2f(unsigned short h) {
    return __uint_as_float(((unsigned)h) << 16);
}

// ---------------------------------------------------------------------------
// conv_row: f32 row-block -> swizzled hi|lo bf16 (chunk c ^ (row&7)).
// ---------------------------------------------------------------------------
__device__ __forceinline__ void conv_row(const float* __restrict__ src,
                                         unsigned short* __restrict__ dst, int t)
{
    int row = t >> 7, rem = t & 127, kb = rem >> 2, c = rem & 3;
    const float* s = src + (size_t)row * IN_DIM + kb * 32 + c * 8;
    float4 v0 = *(const float4*)s;
    float4 v1 = *(const float4*)(s + 4);
    float vv[8] = {v0.x, v0.y, v0.z, v0.w, v1.x, v1.y, v1.z, v1.w};
    bf16x8 H, L;
#pragma unroll
    for (int e = 0; e < 8; ++e) {
        unsigned short h = f2bf(vv[e]);
        H[e] = (short)h;
        L[e] = (short)f2bf(vv[e] - bf2f(h));
    }
    int sw = row & 7;
    unsigned short* base = dst + (size_t)row * 2048 + kb * 64;
    *(bf16x8*)(base + ((c ^ sw) << 3))       = H;
    *(bf16x8*)(base + (((c + 4) ^ sw) << 3)) = L;
}

// ---------------------------------------------------------------------------
// topk body: filter-on-the-fly + wave-0 merge; exact LDS-staged fallback.
// ---------------------------------------------------------------------------
#define TK_THRESH 0.988f

__device__ __forceinline__ void topk_body(int row, const float* __restrict__ adj,
                                          int* __restrict__ topkb)
{
    const int tid  = threadIdx.x;
    const int wave = tid >> 6, lane = tid & 63;
    const float* rp = adj + (size_t)row * N_NODES;

    __shared__ unsigned long long cand[4][64];
    __shared__ int wcnt[4];
    __shared__ float srow[N_NODES];   // fallback stage (16 KB)

    float4 q0 = *(const float4*)(rp + wave * 1024 + 0 * 256 + lane * 4);
    float4 q1 = *(const float4*)(rp + wave * 1024 + 1 * 256 + lane * 4);
    float4 q2 = *(const float4*)(rp + wave * 1024 + 2 * 256 + lane * 4);
    float4 q3 = *(const float4*)(rp + wave * 1024 + 3 * 256 + lane * 4);

    const unsigned long long lmask = (1ull << lane) - 1ull;
    int cnt = 0;

#define FILT(qv, i, e, comp) do {                                             \
        float val = (qv).comp;                                                \
        int g = wave * 1024 + (i) * 256 + lane * 4 + (e);                     \
        bool p = val >= TK_THRESH;                                            \
        unsigned long long m = __ballot(p);                                   \
        if (p) {                                                              \
            int pos = cnt + __popcll(m & lmask);                              \
            if (pos < 64) {                                                   \
                unsigned b  = __float_as_uint(val);                           \
                unsigned mo = b ^ (unsigned)(((int)b >> 31) | 0x80000000);    \
                cand[wave][pos] =                                             \
                    ((unsigned long long)mo << 32) | (unsigned)(N_NODES - 1 - g); \
            }                                                                 \
        }                                                                     \
        cnt += __popcll(m);                                                   \
    } while (0)

    FILT(q0, 0, 0, x); FILT(q0, 0, 1, y); FILT(q0, 0, 2, z); FILT(q0, 0, 3, w);
    FILT(q1, 1, 0, x); FILT(q1, 1, 1, y); FILT(q1, 1, 2, z); FILT(q1, 1, 3, w);
    FILT(q2, 2, 0, x); FILT(q2, 2, 1, y); FILT(q2, 2, 2, z); FILT(q2, 2, 3, w);
    FILT(q3, 3, 0, x); FILT(q3, 3, 1, y); FILT(q3, 3, 2, z); FILT(q3, 3, 3, w);
#undef FILT

    if (lane == 0) wcnt[wave] = cnt;
    __syncthreads();

    const int c0n = wcnt[0], c1n = wcnt[1], c2n = wcnt[2], c3n = wcnt[3];
    const int total = c0n + c1n + c2n + c3n;
    const bool ok = (total >= TOP_K) &&
                    (c0n <= 64) && (c1n <= 64) && (c2n <= 64) && (c3n <= 64);
    int* op = topkb + (size_t)row * TOP_K;

    if (ok) {
        if (wave == 0) {
            unsigned long long k0 = lane < c0n ? cand[0][lane] : 0ull;
            unsigned long long k1 = lane < c1n ? cand[1][lane] : 0ull;
            unsigned long long k2 = lane < c2n ? cand[2][lane] : 0ull;
            unsigned long long k3 = lane < c3n ? cand[3][lane] : 0ull;
            for (int r = 0; r < TOP_K; ++r) {
                unsigned long long a01 = k0 > k1 ? k0 : k1;
                unsigned long long a23 = k2 > k3 ? k2 : k3;
                unsigned long long b = a01 > a23 ? a01 : a23;
#pragma unroll
                for (int m = 1; m < 64; m <<= 1) {
                    unsigned long long o = __shfl_xor(b, m);
                    b = o > b ? o : b;
                }
                if (lane == 0) op[r] = N_NODES - 1 - (int)(unsigned)(b & 0xFFFFFFFFu);
                if (k0 == b) k0 = 0ull;
                if (k1 == b) k1 = 0ull;
                if (k2 == b) k2 = 0ull;
                if (k3 == b) k3 = 0ull;
            }
        }
    } else {
        int base = wave * 1024 + lane * 4;
        *(float4*)&srow[base + 0 * 256] = q0;
        *(float4*)&srow[base + 1 * 256] = q1;
        *(float4*)&srow[base + 2 * 256] = q2;
        *(float4*)&srow[base + 3 * 256] = q3;
        __syncthreads();
        if (wave == 0) {
            for (int r = 0; r < TOP_K; ++r) {
                float bv = -INFINITY; int bg = 0x7fffffff;
                for (int j = 0; j < 64; ++j) {
                    int g = j * 64 + lane;
                    float val = srow[g];
                    bool better = (val > bv) || (val == bv && g < bg);
                    bv = better ? val : bv;
                    bg = better ? g : bg;
                }
#pragma unroll
                for (int m = 1; m < 64; m <<= 1) {
                    float ov = __shfl_xor(bv, m);
                    int   og = __shfl_xor(bg, m);
                    bool better = (ov > bv) || (ov == bv && og < bg);
                    bv = better ? ov : bv;
                    bg = better ? og : bg;
                }
                if (lane == 0) { op[r] = bg; srow[bg] = -INFINITY; }
            }
        }
    }
}

// ---------------------------------------------------------------------------
// Fused launch 1: topk (blocks 0..4095) + prep conversion (4096..6399).
// ---------------------------------------------------------------------------
__global__ __launch_bounds__(256) void prep_topk_kernel(
    const float* __restrict__ x, const float* __restrict__ W,
    unsigned short* __restrict__ xc, unsigned short* __restrict__ wc,
    const float* __restrict__ adj, int* __restrict__ topkb)
{
    int b = blockIdx.x, tid = threadIdx.x;
    if (b < 4096) {
        topk_body(b, adj, topkb);
    } else if (b < 6144) {
        conv_row(x, xc, (b - 4096) * 256 + tid);
    } else {
        conv_row(W, wc, (b - 6144) * 256 + tid);
    }
}

// ---------------------------------------------------------------------------
// GEMM + fused scores.  Tile 64x64, BK=32, 4 waves (2x2), wave-tile 32x32.
// 2 blocks/CU (64 KB LDS/block): co-resident block hides the other's
// vmcnt/barrier stalls.  Depth-3 pipeline, 8 static LDS buffers, steady
// vmcnt(8).  XCD swizzle: xcd owns bm [8x,8x+8) x all bn -> 4 MB = its L2.
// ---------------------------------------------------------------------------
#define GBM 64
#define GBN 64

__global__ __launch_bounds__(256, 2) void gemm_kernel(
    const unsigned short* __restrict__ xc, const unsigned short* __restrict__ wc,
    const float* __restrict__ a, unsigned short* __restrict__ Whb,
    float* __restrict__ spart)
{
    __shared__ __align__(16) unsigned short A0[GBM * 64];   // 8 KB each
    __shared__ __align__(16) unsigned short A1[GBM * 64];
    __shared__ __align__(16) unsigned short A2[GBM * 64];
    __shared__ __align__(16) unsigned short A3[GBM * 64];
    __shared__ __align__(16) unsigned short B0[GBN * 64];   // 8 KB each
    __shared__ __align__(16) unsigned short B1[GBN * 64];
    __shared__ __align__(16) unsigned short B2[GBN * 64];
    __shared__ __align__(16) unsigned short B3[GBN * 64];

    const int tid = threadIdx.x;
    const int id  = blockIdx.x;               // 512 blocks
    const int xcd = id & 7, seq = id >> 3;    // seq 0..63
    const int bm  = xcd * 8 + (seq >> 3), bn = seq & 7;

    const int wave = tid >> 6, lane = tid & 63;
    const int wm = wave >> 1, wn = wave & 1;  // 2x2 wave grid
    const int lr = lane & 15, lk = lane >> 4;

    f32x4 acc[2][2];
#pragma unroll
    for (int i = 0; i < 2; ++i)
#pragma unroll
        for (int j = 0; j < 2; ++j) acc[i][j] = (f32x4){0.f, 0.f, 0.f, 0.f};

#define STAGE(Abuf, Bbuf, kt) do {                                            \
        size_t koff = (size_t)(kt) * 128;                                     \
        _Pragma("unroll")                                                     \
        for (int q = 0; q < 2; ++q) {          /* A: 8 KB = 512 chunks */     \
            int ci = q * 256 + tid;                                           \
            int row = ci >> 3, p = ci & 7;                                    \
            gld16((const char*)xc + ((size_t)(bm * GBM + row) * 4096 + koff + p * 16), \
                  (char*)(Abuf) + (size_t)ci * 16);                           \
        }                                                                     \
        _Pragma("unroll")                                                     \
        for (int q = 0; q < 2; ++q) {          /* B: 8 KB = 512 chunks */     \
            int ci = q * 256 + tid;                                           \
            int row = ci >> 3, p = ci & 7;                                    \
            gld16((const char*)wc + ((size_t)(bn * GBN + row) * 4096 + koff + p * 16), \
                  (char*)(Bbuf) + (size_t)ci * 16);                           \
        }                                                                     \
    } while (0)

#define COMPUTE(Abuf, Bbuf) do {                                              \
        bf16x8 bh[2], bl[2];                                                  \
        _Pragma("unroll")                                                     \
        for (int ni = 0; ni < 2; ++ni) {                                      \
            int rb = wn * 32 + ni * 16 + lr; int swb = rb & 7;                \
            bh[ni] = *(const bf16x8*)&(Bbuf)[rb * 64 + ((lk ^ swb) << 3)];    \
            bl[ni] = *(const bf16x8*)&(Bbuf)[rb * 64 + (((4 + lk) ^ swb) << 3)]; \
        }                                                                     \
        __builtin_amdgcn_s_setprio(1);                                        \
        _Pragma("unroll")                                                     \
        for (int mi = 0; mi < 2; ++mi) {                                      \
            int r = wm * 32 + mi * 16 + lr; int sw = r & 7;                   \
            bf16x8 ah = *(const bf16x8*)&(Abuf)[r * 64 + ((lk ^ sw) << 3)];   \
            bf16x8 al = *(const bf16x8*)&(Abuf)[r * 64 + (((4 + lk) ^ sw) << 3)]; \
            _Pragma("unroll")                                                 \
            for (int ni = 0; ni < 2; ++ni) {                                  \
                acc[mi][ni] = __builtin_amdgcn_mfma_f32_16x16x32_bf16(ah, bh[ni], acc[mi][ni], 0, 0, 0); \
                acc[mi][ni] = __builtin_amdgcn_mfma_f32_16x16x32_bf16(ah, bl[ni], acc[mi][ni], 0, 0, 0); \
                acc[mi][ni] = __builtin_amdgcn_mfma_f32_16x16x32_bf16(al, bh[ni], acc[mi][ni], 0, 0, 0); \
            }                                                                 \
        }                                                                     \
        __builtin_amdgcn_s_setprio(0);                                        \
    } while (0)

#define BODY(Ac, Bc, An, Bn, ktn, W) do {                                     \
        asm volatile("s_waitcnt vmcnt(" #W ")" ::: "memory");                 \
        __builtin_amdgcn_s_barrier();                                         \
        asm volatile("" ::: "memory");                                        \
        if ((ktn) < 32) STAGE(An, Bn, ktn);                                   \
        COMPUTE(Ac, Bc);                                                      \
    } while (0)

    STAGE(A0, B0, 0);
    STAGE(A1, B1, 1);
    STAGE(A2, B2, 2);

    for (int i = 0; i < 7; ++i) {             // t = 0..27, stages 3..30
        BODY(A0, B0, A3, B3, i * 4 + 3, 8);
        BODY(A1, B1, A0, B0, i * 4 + 4, 8);
        BODY(A2, B2, A1, B1, i * 4 + 5, 8);
        BODY(A3, B3, A2, B2, i * 4 + 6, 8);
    }
    BODY(A0, B0, A3, B3, 31, 8);              // t=28, stage 31
    BODY(A1, B1, A0, B0, 33, 8);              // t=29, no stage
    asm volatile("s_waitcnt vmcnt(4)" ::: "memory");
    __builtin_amdgcn_s_barrier();
    asm volatile("" ::: "memory");
    COMPUTE(A2, B2);                          // t=30
    asm volatile("s_waitcnt vmcnt(0)" ::: "memory");
    __builtin_amdgcn_s_barrier();
    asm volatile("" ::: "memory");
    COMPUTE(A3, B3);                          // t=31

#undef BODY
#undef COMPUTE
#undef STAGE

    // ---- epilogue: bf16 Wh store + score partials to private slot ----
    const int h = bn >> 1;                     // head uniform per block
    float* sps = spart + ((size_t)((bn & 1) * 2 + wn)) * 16384;
    float* spd = spart + 65536 + ((size_t)((bn & 1) * 2 + wn)) * 16384;
    float ca[2], cb[2];
#pragma unroll
    for (int ni = 0; ni < 2; ++ni) {
        int dcol = (bn & 1) * 64 + wn * 32 + ni * 16 + lr;
        ca[ni] = a[dcol];
        cb[ni] = a[HEAD_DIM + dcol];
    }
#pragma unroll
    for (int mi = 0; mi < 2; ++mi) {
        float ss[4] = {0.f, 0.f, 0.f, 0.f}, sd[4] = {0.f, 0.f, 0.f, 0.f};
#pragma unroll
        for (int ni = 0; ni < 2; ++ni) {
            int col_g = bn * GBN + wn * 32 + ni * 16 + lr;
#pragma unroll
            for (int r = 0; r < 4; ++r) {
                int row_g = bm * GBM + wm * 32 + mi * 16 + lk * 4 + r;
                float v = acc[mi][ni][r];
                Whb[(size_t)row_g * OUT_DIM + col_g] = f2bf(v);
                ss[r] += v * ca[ni];
                sd[r] += v * cb[ni];
            }
        }
#pragma unroll
        for (int s = 1; s < 16; s <<= 1)
#pragma unroll
            for (int r = 0; r < 4; ++r) {
                ss[r] += __shfl_xor(ss[r], s);
                sd[r] += __shfl_xor(sd[r], s);
            }
        if (lr == 0) {
#pragma unroll
            for (int r = 0; r < 4; ++r) {
                int row_g = bm * GBM + wm * 32 + mi * 16 + lk * 4 + r;
                sps[row_g * NUM_HEADS + h] = ss[r];
                spd[row_g * NUM_HEADS + h] = sd[r];
            }
        }
    }
}

// ---------------------------------------------------------------------------
// Aggregate (bf16 Wh): wave-parallel softmax (scores = sum of 4 partial
// slots), gather 4 neighbor-groups x 64 col-octets, LDS combine, ELU.
// ---------------------------------------------------------------------------
__global__ __launch_bounds__(256) void aggregate_kernel(
    const unsigned short* __restrict__ Whb, const int* __restrict__ topk,
    const float* __restrict__ spart, float* __restrict__ out)
{
    const int i = blockIdx.x, t = threadIdx.x;
    __shared__ int   sidx[TOP_K];
    __shared__ float salpha[TOP_K][NUM_HEADS];
    __shared__ float part[3][8][64];

    if (t < 64) {
        int idxv = 0;
        if (t < TOP_K) { idxv = topk[(size_t)i * TOP_K + t]; sidx[t] = idxv; }
        int m = t >> 2, h = t & 3;
        int im = __shfl(idxv, m);
        int si = (i << 2) + h, di = (im << 2) + h;
        float e = spart[si] + spart[16384 + si] + spart[32768 + si] + spart[49152 + si]
                + spart[65536 + di] + spart[81920 + di] + spart[98304 + di] + spart[114688 + di];
        e = (e >= 0.f) ? e : NEG_SLOPE * e;
        float mx = e;
#pragma unroll
        for (int s = 4; s < 64; s <<= 1) mx = fmaxf(mx, __shfl_xor(mx, s));
        float ex = expf(e - mx);
        float sum = ex;
#pragma unroll
        for (int s = 4; s < 64; s <<= 1) sum += __shfl_xor(sum, s);
        salpha[m][h] = ex / sum;
    }
    __syncthreads();

    const int g = t >> 6, o = t & 63;       // group g: neighbors 4g..4g+3
    const int h = o >> 4;                   // cols 8o..8o+7 all in head h
    float acc8[8] = {0.f, 0.f, 0.f, 0.f, 0.f, 0.f, 0.f, 0.f};
#pragma unroll
    for (int q = 0; q < 4; ++q) {
        int m = g * 4 + q;
        float al = salpha[m][h];
        bf16x8 v = *(const bf16x8*)&Whb[(size_t)sidx[m] * OUT_DIM + o * 8];
#pragma unroll
        for (int e = 0; e < 8; ++e)
            acc8[e] += al * bf2f((unsigned short)v[e]);
    }
    if (g) {
#pragma unroll
        for (int e = 0; e < 8; ++e) part[g - 1][e][o] = acc8[e];
    }
    __syncthreads();
    if (!g) {
        float r8[8];
#pragma unroll
        for (int e = 0; e < 8; ++e) {
            float s = acc8[e] + part[0][e][o] + part[1][e][o] + part[2][e][o];
            r8[e] = s > 0.f ? s : expf(s) - 1.f;
        }
        float4 lo = (float4){r8[0], r8[1], r8[2], r8[3]};
        float4 hi = (float4){r8[4], r8[5], r8[6], r8[7]};
        *(float4*)(out + (size_t)i * OUT_DIM + o * 8)     = lo;
        *(float4*)(out + (size_t)i * OUT_DIM + o * 8 + 4) = hi;
    }
}

// ---------------------------------------------------------------------------
extern "C" void kernel_launch(void* const* d_in, const int* in_sizes, int n_in,
                              void* d_out, int out_size, void* d_ws, size_t ws_size,
                              hipStream_t stream) {
    const float* x   = (const float*)d_in[0];
    const float* adj = (const float*)d_in[1];
    const float* W   = (const float*)d_in[2];
    const float* a   = (const float*)d_in[3];
    float* out = (float*)d_out;

    char* ws = (char*)d_ws;
    unsigned short* Whb   = (unsigned short*)ws;                         //  4 MB
    unsigned short* xc    = (unsigned short*)(ws + (8u << 20));          // 16 MB
    unsigned short* wc    = (unsigned short*)(ws + (24u << 20));         //  2 MB
    float*          spart = (float*)(ws + (26u << 20));                  // 512 KB
    int*            topkb = (int*)(ws + (26u << 20) + (512u << 10));     // 256 KB

    prep_topk_kernel<<<6400, 256, 0, stream>>>(x, W, xc, wc, adj, topkb);
    gemm_kernel<<<512, 256, 0, stream>>>(xc, wc, a, Whb, spart);
    aggregate_kernel<<<N_NODES, 256, 0, stream>>>(Whb, topkb, spart, out);
}